// Round 7
// baseline (346.943 us; speedup 1.0000x reference)
//
#include <hip/hip_runtime.h>
#include <stdint.h>

#define NU 100000
#define NI 200000
#define NT 300000          // NU + NI
#define D 64
#define NNZ 1200000
#define NHOPS 3
#define SL 4               // slices per row = NHOPS+1
#define ROWF (SL * D)      // 256 floats per output row
#define KS 8               // padded kept-edge slots per row (R6 mid path)
#define KA 16              // padded adjacency slots per row (fast path)
#define OVF_CAP 16384

__host__ __device__ __forceinline__ uint32_t rotl32(uint32_t x, int r) {
    return (x << r) | (x >> (32 - r));
}

// Threefry-2x32, 20 rounds — matches jax._src.prng.threefry2x32
__host__ __device__ inline void tf2x32(uint32_t k0, uint32_t k1,
                                       uint32_t x0, uint32_t x1,
                                       uint32_t& o0, uint32_t& o1) {
    uint32_t ks0 = k0, ks1 = k1, ks2 = k0 ^ k1 ^ 0x1BD11BDAu;
    x0 += ks0; x1 += ks1;
#define RND(r) { x0 += x1; x1 = rotl32(x1, r); x1 ^= x0; }
    RND(13) RND(15) RND(26) RND(6)
    x0 += ks1; x1 += ks2 + 1u;
    RND(17) RND(29) RND(16) RND(24)
    x0 += ks2; x1 += ks0 + 2u;
    RND(13) RND(15) RND(26) RND(6)
    x0 += ks0; x1 += ks1 + 3u;
    RND(17) RND(29) RND(16) RND(24)
    x0 += ks1; x1 += ks2 + 4u;
    RND(13) RND(15) RND(26) RND(6)
    o0 = x0 + ks2; o1 = x1 + ks0 + 5u;
#undef RND
}

__device__ __forceinline__ uint32_t rbits(uint32_t k0, uint32_t k1, uint32_t j) {
    uint32_t o0, o1;
    tf2x32(k0, k1, 0u, j, o0, o1);
    return o0 ^ o1;
}

__device__ __forceinline__ float u01(uint32_t bits) {
    return __uint_as_float((bits >> 9) | 0x3f800000u) - 1.0f;
}

// keep edge  <=> u >= 0.5  <=> top bit of bits        (exact)
// keep mess  <=> u < 0.9f  <=> (bits>>9) < 7549747    (exact: 0.9f*2^23 = 7549747)
#define MESS_KEEP_T 7549747u

// ------------------------- fast (adjacency) path -------------------------

// build full adjacency once: aslot[r*KA+pos] = {col, eid, val_bits, 0}
__global__ void build_adj_kernel(const int* __restrict__ rows,
                                 const int* __restrict__ cols,
                                 const float* __restrict__ vals,
                                 int* __restrict__ acnt,
                                 int4* __restrict__ aslot,
                                 int4* __restrict__ ovf) {
    int e = blockIdx.x * blockDim.x + threadIdx.x;
    if (e >= NNZ) return;
    int r = rows[e];
    int pos = atomicAdd(&acnt[r], 1);
    if (pos < KA) {
        aslot[(size_t)r * KA + pos] = make_int4(cols[e], e, __float_as_int(vals[e]), 0);
    } else {
        int oi = atomicAdd(&acnt[NT], 1);
        if (oi < OVF_CAP) ovf[oi] = make_int4(r, cols[e], e, __float_as_int(vals[e]));
    }
}

// 8 rows per wave; per-lane edge RNG on 2 owned slots; mess-drop fused.
template <int H0>
__launch_bounds__(256)
__global__ void spmmA_kernel(const int* __restrict__ acnt,
                             const int4* __restrict__ aslot,
                             const int4* __restrict__ ovf,
                             const float* __restrict__ ue,
                             const float* __restrict__ ie,
                             float* __restrict__ out, int hop,
                             uint32_t ke0, uint32_t ke1,
                             uint32_t km0, uint32_t km1) {
    int w    = (blockIdx.x * blockDim.x + threadIdx.x) >> 6;
    int lane = threadIdx.x & 63;
    int r0   = w * 8;
    if (r0 >= NT) return;                       // NT % 8 == 0

    // ---- stage 1: all independent loads up front ----
    int mk0 = 0;
    if (lane < 8) mk0 = acnt[r0 + lane];
    const int4* base = aslot + (size_t)r0 * KA;  // 8 rows x 16 slots = 128 int4
    int4 s0 = base[lane];                        // slots 0..63   (rows 0..3)
    int4 s1 = base[lane + 64];                   // slots 64..127 (rows 4..7)

    float4 e04a, e04b;
    if (H0) {
        // NU % 8 == 0 -> all 8 rows on the same side of the user/item split
        const float4* s4 = (r0 < NU) ? (const float4*)(ue + (size_t)r0 * D)
                                     : (const float4*)(ie + (size_t)(r0 - NU) * D);
        e04a = s4[lane];
        e04b = s4[lane + 64];
    }

    // ---- per-lane edge RNG + validity mask on the 2 owned slots ----
    // slot s: row = s>>4, j = s&15; valid iff j < acnt[row]
    int a0 = __shfl(mk0, lane >> 4, 64);               // count for row of slot  lane
    int a1 = __shfl(mk0, (lane >> 4) + 4, 64);         // count for row of slot  lane+64
    uint32_t b0 = rbits(ke0, ke1, (uint32_t)s0.y);
    uint32_t b1 = rbits(ke0, ke1, (uint32_t)s1.y);
    bool k0 = ((b0 & 0x80000000u) != 0u) && ((lane & 15) < a0);
    bool k1 = ((b1 & 0x80000000u) != 0u) && ((lane & 15) < a1);
    float v0 = k0 ? __int_as_float(s0.z) * 2.0f : 0.0f;
    float v1 = k1 ? __int_as_float(s1.z) * 2.0f : 0.0f;
    int   c0 = k0 ? s0.x : 0;
    int   c1 = k1 ? s1.x : 0;

    // ---- wave-max full degree (lanes 0..7 hold counts) ----
    int mkr = mk0;
    mkr = max(mkr, __shfl_xor(mkr, 1, 64));
    mkr = max(mkr, __shfl_xor(mkr, 2, 64));
    mkr = max(mkr, __shfl_xor(mkr, 4, 64));
    int mxf = __shfl(mkr, 0, 64);
    int mx  = (mxf < KA) ? mxf : KA;

    float acc[8] = {0.f, 0.f, 0.f, 0.f, 0.f, 0.f, 0.f, 0.f};

    // ---- gather loop: 8 independent 256B gathers per iteration ----
    for (int j = 0; j < mx; ++j) {
        float vv[8]; int cc[8];
        #pragma unroll
        for (int r = 0; r < 8; ++r) {
            int sl = (r * KA + j) & 63;          // lane holding this slot
            vv[r] = __shfl((r < 4) ? v0 : v1, sl, 64);
            cc[r] = __shfl((r < 4) ? c0 : c1, sl, 64);
        }
        float g[8];
        #pragma unroll
        for (int r = 0; r < 8; ++r) {
            if (H0) {
                const float* b = (cc[r] < NU) ? ue : ie;
                int c2 = (cc[r] < NU) ? cc[r] : cc[r] - NU;
                g[r] = b[(size_t)c2 * D + lane];
            } else {
                g[r] = out[(size_t)cc[r] * ROWF + (size_t)hop * D + lane];
            }
        }
        #pragma unroll
        for (int r = 0; r < 8; ++r) acc[r] += vv[r] * g[r];
    }

    // ---- cold overflow: rows with degree > KA (P ~ 3e-7) ----
    if (mxf > KA) {
        int no = acnt[NT];
        if (no > OVF_CAP) no = OVF_CAP;
        #pragma unroll
        for (int r = 0; r < 8; ++r) {            // static acc index
            int mr = __shfl(mk0, r, 64);
            if (mr > KA) {
                for (int i = 0; i < no; ++i) {
                    int4 ent = ovf[i];
                    if (ent.x == r0 + r) {
                        uint32_t be = rbits(ke0, ke1, (uint32_t)ent.z);
                        if (be & 0x80000000u) {
                            float src;
                            if (H0) {
                                const float* b = (ent.y < NU) ? ue : ie;
                                int c2 = (ent.y < NU) ? ent.y : ent.y - NU;
                                src = b[(size_t)c2 * D + lane];
                            } else {
                                src = out[(size_t)ent.y * ROWF + (size_t)hop * D + lane];
                            }
                            acc[r] += __int_as_float(ent.w) * 2.0f * src;
                        }
                    }
                }
            }
        }
    }

    // ---- fused hop-0 slice-0 copy ----
    if (H0) {
        int f0 = lane, f1 = lane + 64;
        ((float4*)out)[(size_t)(r0 + (f0 >> 4)) * 64 + (f0 & 15)] = e04a;
        ((float4*)out)[(size_t)(r0 + (f1 >> 4)) * 64 + (f1 & 15)] = e04b;
    }

    // ---- fused message dropout + store ----
    const float INVM = (float)(1.0 / (1.0 - 0.1));
    #pragma unroll
    for (int r = 0; r < 8; ++r) {
        uint32_t t = rbits(km0, km1, (uint32_t)((r0 + r) * D + lane)) >> 9;
        float a = (t < MESS_KEEP_T) ? acc[r] * INVM : 0.0f;
        out[(size_t)(r0 + r) * ROWF + (size_t)(hop + 1) * D + lane] = a;
    }
}

// ------------------------- R6 mid path -------------------------

__global__ void zero_kernel(int* __restrict__ p, int n) {
    int i = blockIdx.x * blockDim.x + threadIdx.x;
    if (i < n) p[i] = 0;
}

__global__ void scat_kernel(const int* __restrict__ rows,
                            const int* __restrict__ cols,
                            const float* __restrict__ vals,
                            int* __restrict__ kcnt,
                            int2* __restrict__ kslot,
                            int4* __restrict__ ovf,
                            uint32_t ke0, uint32_t ke1) {
    int e = blockIdx.x * blockDim.x + threadIdx.x;
    if (e >= NNZ) return;
    uint32_t b = rbits(ke0, ke1, (uint32_t)e);
    if (!(b & 0x80000000u)) return;
    int r = rows[e];
    int c = cols[e];
    float v2 = vals[e] * 2.0f;
    int pos = atomicAdd(&kcnt[r], 1);
    if (pos < KS) {
        kslot[(size_t)r * KS + pos] = make_int2(c, __float_as_int(v2));
    } else {
        int oi = atomicAdd(&kcnt[NT], 1);
        if (oi < OVF_CAP) ovf[oi] = make_int4(r, c, __float_as_int(v2), 0);
    }
}

template <int H0>
__global__ void spmm8_kernel(const int* __restrict__ kcnt,
                             const int2* __restrict__ kslot,
                             const int4* __restrict__ ovf,
                             const float* __restrict__ ue,
                             const float* __restrict__ ie,
                             float* __restrict__ out, int hop,
                             uint32_t km0, uint32_t km1) {
    int w    = (blockIdx.x * blockDim.x + threadIdx.x) >> 6;
    int lane = threadIdx.x & 63;
    int r0   = w * 8;
    if (r0 >= NT) return;

    int mk = 0;
    if (lane < 8) mk = kcnt[r0 + lane];
    int2 kp = kslot[(size_t)r0 * KS + lane];

    float4 e04a, e04b;
    if (H0) {
        const float4* s4 = (r0 < NU) ? (const float4*)(ue + (size_t)r0 * D)
                                     : (const float4*)(ie + (size_t)(r0 - NU) * D);
        e04a = s4[lane];
        e04b = s4[lane + 64];
    }

    int   cl = kp.x;
    float vl = __int_as_float(kp.y);

    int m[8];
    #pragma unroll
    for (int r = 0; r < 8; ++r) m[r] = __shfl(mk, r, 64);
    int mxf = 0;
    #pragma unroll
    for (int r = 0; r < 8; ++r) mxf = max(mxf, m[r]);
    int mx = (mxf < KS) ? mxf : KS;

    float acc[8] = {0.f, 0.f, 0.f, 0.f, 0.f, 0.f, 0.f, 0.f};

    for (int j = 0; j < mx; ++j) {
        float vv[8]; int cc[8];
        #pragma unroll
        for (int r = 0; r < 8; ++r) {
            int slot = r * KS + j;
            float v = __shfl(vl, slot, 64);
            int   c = __shfl(cl, slot, 64);
            bool ok = (j < m[r]);
            vv[r] = ok ? v : 0.0f;
            cc[r] = ok ? c : 0;
        }
        float g[8];
        #pragma unroll
        for (int r = 0; r < 8; ++r) {
            if (H0) {
                const float* b = (cc[r] < NU) ? ue : ie;
                int c2 = (cc[r] < NU) ? cc[r] : cc[r] - NU;
                g[r] = b[(size_t)c2 * D + lane];
            } else {
                g[r] = out[(size_t)cc[r] * ROWF + (size_t)hop * D + lane];
            }
        }
        #pragma unroll
        for (int r = 0; r < 8; ++r) acc[r] += vv[r] * g[r];
    }

    if (mxf > KS) {
        int no = kcnt[NT];
        if (no > OVF_CAP) no = OVF_CAP;
        #pragma unroll
        for (int r = 0; r < 8; ++r) {
            if (m[r] > KS) {
                for (int i = 0; i < no; ++i) {
                    int4 ent = ovf[i];
                    if (ent.x == r0 + r) {
                        float src;
                        if (H0) {
                            const float* b = (ent.y < NU) ? ue : ie;
                            int c2 = (ent.y < NU) ? ent.y : ent.y - NU;
                            src = b[(size_t)c2 * D + lane];
                        } else {
                            src = out[(size_t)ent.y * ROWF + (size_t)hop * D + lane];
                        }
                        acc[r] += __int_as_float(ent.z) * src;
                    }
                }
            }
        }
    }

    if (H0) {
        int f0 = lane, f1 = lane + 64;
        ((float4*)out)[(size_t)(r0 + (f0 >> 4)) * 64 + (f0 & 15)] = e04a;
        ((float4*)out)[(size_t)(r0 + (f1 >> 4)) * 64 + (f1 & 15)] = e04b;
    }

    const float INVM = (float)(1.0 / (1.0 - 0.1));
    #pragma unroll
    for (int r = 0; r < 8; ++r) {
        uint32_t t = rbits(km0, km1, (uint32_t)((r0 + r) * D + lane)) >> 9;
        float a = (t < MESS_KEEP_T) ? acc[r] * INVM : 0.0f;
        out[(size_t)(r0 + r) * ROWF + (size_t)(hop + 1) * D + lane] = a;
    }
}

// ------------------------- R1 small-ws fallback -------------------------

__global__ void init_kernel(const float4* __restrict__ ue,
                            const float4* __restrict__ ie,
                            float4* __restrict__ out) {
    int gid = blockIdx.x * blockDim.x + threadIdx.x;
    if (gid >= NT * 16) return;
    int n = gid >> 4, q = gid & 15;
    float4 v = (n < NU) ? ue[n * 16 + q] : ie[(n - NU) * 16 + q];
    float4 z = make_float4(0.f, 0.f, 0.f, 0.f);
    float4* row = out + (size_t)n * 64;
    row[q]      = v;
    row[16 + q] = z;
    row[32 + q] = z;
    row[48 + q] = z;
}

__global__ void spmm_inline_kernel(const float* __restrict__ vals,
                                   const int* __restrict__ rows,
                                   const int* __restrict__ cols,
                                   float* __restrict__ out, int hop,
                                   uint32_t ke0, uint32_t ke1) {
    int wid  = (blockIdx.x * blockDim.x + threadIdx.x) >> 6;
    int lane = threadIdx.x & 63;
    if (wid >= NNZ) return;
    float u = u01(rbits(ke0, ke1, (uint32_t)wid));
    if (u < 0.5f) return;
    float ve = vals[wid] * 2.0f;
    int r = rows[wid], c = cols[wid];
    float x = out[c * ROWF + hop * D + lane];
    unsafeAtomicAdd(&out[r * ROWF + (hop + 1) * D + lane], ve * x);
}

__global__ void mess_drop_kernel(float* __restrict__ out, int hop,
                                 uint32_t km0, uint32_t km1) {
    int j = blockIdx.x * blockDim.x + threadIdx.x;
    if (j >= NT * D) return;
    uint32_t t = rbits(km0, km1, (uint32_t)j) >> 9;
    int n = j >> 6, d = j & 63;
    int idx = n * ROWF + (hop + 1) * D + d;
    const float INVM = (float)(1.0 / (1.0 - 0.1));
    float a = out[idx];
    out[idx] = (t < MESS_KEEP_T) ? a * INVM : 0.0f;
}

// ------------------------- launch -------------------------

extern "C" void kernel_launch(void* const* d_in, const int* in_sizes, int n_in,
                              void* d_out, int out_size, void* d_ws, size_t ws_size,
                              hipStream_t stream) {
    const float* ue   = (const float*)d_in[0];
    const float* ie   = (const float*)d_in[1];
    const float* vals = (const float*)d_in[2];
    const int*   rows = (const int*)d_in[3];
    const int*   cols = (const int*)d_in[4];
    float* out = (float*)d_out;

    // fast path ws layout: acnt (NT+1 ints) | aslot (NT*KA int4) | ovf
    const size_t off_acnt  = 0;
    const size_t off_aslot = 1200016;
    const size_t off_aovf  = off_aslot + (size_t)NT * KA * 16;    // 78,000,016
    const size_t need_adj  = off_aovf + (size_t)OVF_CAP * 16;     // 78,262,160

    // mid (R6) ws layout: kcnt | kslot | ovf
    const size_t off_kcnt  = 0;
    const size_t off_kslot = 1200016;
    const size_t off_kovf  = off_kslot + (size_t)NT * KS * 8;     // 20,400,016
    const size_t need_mid  = off_kovf + (size_t)OVF_CAP * 16;     // 20,662,160

    uint32_t kf0, kf1;
    uint32_t ke0[NHOPS], ke1[NHOPS], km0[NHOPS], km1[NHOPS];
    for (int h = 0; h < NHOPS; ++h) {
        tf2x32(0u, 42u, 0u, (uint32_t)h, kf0, kf1);
        tf2x32(kf0, kf1, 0u, 0u, ke0[h], ke1[h]);
        tf2x32(kf0, kf1, 0u, 1u, km0[h], km1[h]);
    }

    if (ws_size >= need_adj) {
        int*  acnt  = (int*)((char*)d_ws + off_acnt);
        int4* aslot = (int4*)((char*)d_ws + off_aslot);
        int4* aovf  = (int4*)((char*)d_ws + off_aovf);

        hipMemsetAsync(acnt, 0, (NT + 1) * sizeof(int), stream);
        build_adj_kernel<<<(NNZ + 255) / 256, 256, 0, stream>>>(
            rows, cols, vals, acnt, aslot, aovf);

        for (int h = 0; h < NHOPS; ++h) {
            if (h == 0)
                spmmA_kernel<1><<<(NT / 8 * 64 + 255) / 256, 256, 0, stream>>>(
                    acnt, aslot, aovf, ue, ie, out, h,
                    ke0[h], ke1[h], km0[h], km1[h]);
            else
                spmmA_kernel<0><<<(NT / 8 * 64 + 255) / 256, 256, 0, stream>>>(
                    acnt, aslot, aovf, ue, ie, out, h,
                    ke0[h], ke1[h], km0[h], km1[h]);
        }
    } else if (ws_size >= need_mid) {
        int*  kcnt  = (int*)((char*)d_ws + off_kcnt);
        int2* kslot = (int2*)((char*)d_ws + off_kslot);
        int4* kovf  = (int4*)((char*)d_ws + off_kovf);

        for (int h = 0; h < NHOPS; ++h) {
            zero_kernel<<<(NT + 1 + 255) / 256, 256, 0, stream>>>(kcnt, NT + 1);
            scat_kernel<<<(NNZ + 255) / 256, 256, 0, stream>>>(
                rows, cols, vals, kcnt, kslot, kovf, ke0[h], ke1[h]);
            if (h == 0)
                spmm8_kernel<1><<<(NT / 8 * 64 + 255) / 256, 256, 0, stream>>>(
                    kcnt, kslot, kovf, ue, ie, out, h, km0[h], km1[h]);
            else
                spmm8_kernel<0><<<(NT / 8 * 64 + 255) / 256, 256, 0, stream>>>(
                    kcnt, kslot, kovf, ue, ie, out, h, km0[h], km1[h]);
        }
    } else {
        init_kernel<<<(NT * 16 + 255) / 256, 256, 0, stream>>>(
            (const float4*)ue, (const float4*)ie, (float4*)out);
        for (int h = 0; h < NHOPS; ++h) {
            spmm_inline_kernel<<<(NNZ + 3) / 4, 256, 0, stream>>>(
                vals, rows, cols, out, h, ke0[h], ke1[h]);
            mess_drop_kernel<<<(NT * D + 255) / 256, 256, 0, stream>>>(out, h, km0[h], km1[h]);
        }
    }
}